// Round 16
// baseline (250.229 us; speedup 1.0000x reference)
//
#include <hip/hip_runtime.h>
#include <cstdint>
#include <cstddef>

// Problem constants (B,S,D,H) = (2, 2048, 256, 8)
#define S_LEN 2048
#define DIM   256
#define NH    8
#define NB    2
#define HDIM  (NH * DIM)   // 2048

using bf16 = __bf16;
typedef __bf16 bf16x8 __attribute__((ext_vector_type(8)));
typedef __bf16 bf16x4 __attribute__((ext_vector_type(4)));
typedef float  f32x4  __attribute__((ext_vector_type(4)));
typedef float  f32x16 __attribute__((ext_vector_type(16)));

typedef const __attribute__((address_space(1))) unsigned int* as1_u32p;
typedef __attribute__((address_space(3))) unsigned int* as3_u32p;

// async 16B global -> LDS (no VGPR round-trip). LDS dest = wave-uniform base
// + lane*16 (m104/m108).
__device__ __forceinline__ void cp16(const bf16* g, bf16* l) {
    __builtin_amdgcn_global_load_lds((as1_u32p)g, (as3_u32p)l, 16, 0, 0);
}

// ---------------------------------------------------------------------------
// Fused prep (one launch): z=0..2 -> wQ/wK/wV transpose-cast (h = y>>2),
// z=3 -> wO transpose-cast, z=4 -> X fp32->bf16 cast. grid dim3(4,32,5).
// ---------------------------------------------------------------------------
__global__ __launch_bounds__(256) void prep_kernel(const float* __restrict__ X,
                                                   const float* __restrict__ wQ,
                                                   const float* __restrict__ wK,
                                                   const float* __restrict__ wV,
                                                   const float* __restrict__ wO,
                                                   bf16* __restrict__ Xb,
                                                   bf16* __restrict__ WQt,
                                                   bf16* __restrict__ WKt,
                                                   bf16* __restrict__ WVt,
                                                   bf16* __restrict__ WOt)
{
    const int z = blockIdx.z;
    if (z == 4) {                     // cast X
        const int t = (blockIdx.y*4 + blockIdx.x)*256 + threadIdx.x;   // 0..32767
        #pragma unroll
        for (int p = 0; p < 8; ++p) {
            const int i = (t + p*32768)*4;
            float4 v = *(const float4*)(X + i);
            bf16x4 o;
            o[0] = (bf16)v.x; o[1] = (bf16)v.y; o[2] = (bf16)v.z; o[3] = (bf16)v.w;
            *(bf16x4*)(Xb + i) = o;
        }
        return;
    }
    __shared__ float tile[64][65];
    const float* in; bf16* out; int R, C, r0, c0;
    if (z < 3) {
        const int h = blockIdx.y >> 2;
        in  = (z == 0 ? wQ : z == 1 ? wK : wV) + (size_t)h * DIM * DIM;
        out = (z == 0 ? WQt : z == 1 ? WKt : WVt) + (size_t)h * DIM * DIM;
        R = DIM; C = DIM; r0 = (blockIdx.y & 3) * 64; c0 = blockIdx.x * 64;
    } else {
        in = wO; out = WOt; R = HDIM; C = DIM;
        r0 = blockIdx.y * 64; c0 = blockIdx.x * 64;
    }
    const int tr  = threadIdx.x >> 4;
    const int tc4 = (threadIdx.x & 15) * 4;
    #pragma unroll
    for (int p = 0; p < 4; ++p) {
        int row = p * 16 + tr;
        float4 v = *(const float4*)(in + (size_t)(r0 + row) * C + c0 + tc4);
        tile[row][tc4+0] = v.x; tile[row][tc4+1] = v.y;
        tile[row][tc4+2] = v.z; tile[row][tc4+3] = v.w;
    }
    __syncthreads();
    #pragma unroll
    for (int p = 0; p < 4; ++p) {
        int orow = p * 16 + tr;
        bf16x4 o;
        #pragma unroll
        for (int j = 0; j < 4; ++j) o[j] = (bf16)tile[tc4 + j][orow];
        *(bf16x4*)(out + (size_t)(c0 + orow) * R + r0 + tc4) = o;
    }
}

// ---------------------------------------------------------------------------
// 128x128-tile bf16 MFMA GEMM, ROUND-8/14-verified (async-DMA, XOR swizzle,
// single barrier per k-step). EPI: 0 bf16, 1 f32 store.
// ---------------------------------------------------------------------------
template<int EPI>
__device__ __forceinline__ void gemm_tile(const bf16* __restrict__ A, const bf16* __restrict__ BT,
                                          void* __restrict__ C, bf16* As, bf16* Bs,
                                          int tm, int tn, int K, int lda, int ldb, int ldc)
{
    const int tid  = threadIdx.x;
    const int lane = tid & 63;
    const int wave = tid >> 6;
    const int wm   = (wave >> 1) << 6;
    const int wn   = (wave & 1) << 6;
    const int l16  = lane & 15;
    const int quad = lane >> 4;

    const int m0 = tm << 7, n0 = tn << 7;

    const int srow = (lane >> 2);
    const int gch  = (lane & 3) ^ (srow & 3);

    f32x4 acc[4][4] = {};

    const int ksteps = K >> 5;

    #pragma unroll
    for (int j = 0; j < 2; ++j) {
        const int g = wave*2 + j;
        cp16(A  + (size_t)(m0 + g*16 + srow)*lda + (gch << 3), As + g*512);
        cp16(BT + (size_t)(n0 + g*16 + srow)*ldb + (gch << 3), Bs + g*512);
    }

    for (int ks = 0; ks < ksteps; ++ks) {
        const int pb = ks & 1;
        asm volatile("s_waitcnt vmcnt(0)" ::: "memory");
        __syncthreads();
        if (ks + 1 < ksteps) {
            const int k1 = (ks + 1) << 5;
            #pragma unroll
            for (int j = 0; j < 2; ++j) {
                const int g = wave*2 + j;
                cp16(A  + (size_t)(m0 + g*16 + srow)*lda + k1 + (gch << 3),
                     As + (pb ^ 1)*4096 + g*512);
                cp16(BT + (size_t)(n0 + g*16 + srow)*ldb + k1 + (gch << 3),
                     Bs + (pb ^ 1)*4096 + g*512);
            }
        }
        const bf16* Ab = As + pb*4096;
        const bf16* Bb = Bs + pb*4096;
        bf16x8 af[4], bfv[4];
        #pragma unroll
        for (int i = 0; i < 4; ++i) {
            const int row = wm + i*16 + l16;
            af[i]  = *(const bf16x8*)(Ab + row*32 + ((quad ^ (l16 & 3)) << 3));
        }
        #pragma unroll
        for (int i = 0; i < 4; ++i) {
            const int row = wn + i*16 + l16;
            bfv[i] = *(const bf16x8*)(Bb + row*32 + ((quad ^ (l16 & 3)) << 3));
        }
        #pragma unroll
        for (int i = 0; i < 4; ++i)
            #pragma unroll
            for (int j = 0; j < 4; ++j)
                acc[i][j] = __builtin_amdgcn_mfma_f32_16x16x32_bf16(af[i], bfv[j], acc[i][j], 0, 0, 0);
    }

    #pragma unroll
    for (int i = 0; i < 4; ++i)
        #pragma unroll
        for (int j = 0; j < 4; ++j)
            #pragma unroll
            for (int r = 0; r < 4; ++r) {
                int mg = m0 + wm + i*16 + quad*4 + r;
                int ng = n0 + wn + j*16 + l16;
                float v = acc[i][j][r];
                if (EPI == 0) ((bf16*)C)[(size_t)mg * ldc + ng] = (bf16)v;
                else          ((float*)C)[(size_t)mg * ldc + ng] = v;
            }
}

// QKV projections. grid = (32 tiles, 48 = {Q,K,V} x b x h). LDS 32 KB.  [R14]
__global__ __launch_bounds__(256) void proj_kernel(const bf16* __restrict__ Xb,
    const bf16* __restrict__ WQt, const bf16* __restrict__ WKt, const bf16* __restrict__ WVt,
    bf16* __restrict__ Qg, bf16* __restrict__ Kg, bf16* __restrict__ VTg)
{
    __shared__ __align__(16) bf16 smem[4 * 4096];
    const int by  = blockIdx.y;
    const int mat = by >> 4;
    const int b   = (by >> 3) & 1;
    const int h   = by & 7;
    const int bx  = blockIdx.x;
    const bf16*  Xbb = Xb + (size_t)b * S_LEN * DIM;
    const size_t bh  = (size_t)(b * NH + h);
    if (mat == 0) {
        gemm_tile<0>(Xbb, WQt + (size_t)h*DIM*DIM, Qg + bh*S_LEN*DIM, smem, smem + 8192,
                     bx & 15, bx >> 4, DIM, DIM, DIM, DIM);
    } else if (mat == 1) {
        gemm_tile<0>(Xbb, WKt + (size_t)h*DIM*DIM, Kg + bh*S_LEN*DIM, smem, smem + 8192,
                     bx & 15, bx >> 4, DIM, DIM, DIM, DIM);
    } else {
        gemm_tile<0>(WVt + (size_t)h*DIM*DIM, Xbb, VTg + bh*DIM*S_LEN, smem, smem + 8192,
                     bx & 1, bx >> 1, DIM, DIM, DIM, S_LEN);
    }
}

// outproj to 4 fp32 slabs (no atomics): slab[kq][4096][256] = Ret@WOt k-slice. [R14]
__global__ __launch_bounds__(256) void outproj_kernel(const bf16* __restrict__ Ret,
                                                      const bf16* __restrict__ WOt,
                                                      float* __restrict__ slabs)
{
    __shared__ __align__(16) bf16 smem[4 * 4096];
    int bx = blockIdx.x;
    int t  = bx & 63;
    int kq = bx >> 6;
    gemm_tile<1>(Ret + kq*512, WOt + kq*512, slabs + (size_t)kq*4096*256,
                 smem, smem + 8192, t >> 1, t & 1, 512, HDIM, HDIM, DIM);
}

// sum 4 slabs -> d_out. 1024 blocks x 256 thr x float4. [R14]
__global__ __launch_bounds__(256) void reduce_out_kernel(const float* __restrict__ slabs,
                                                         float* __restrict__ out)
{
    const size_t i = ((size_t)blockIdx.x*256 + threadIdx.x)*4;
    const size_t N = (size_t)4096*256;
    float4 a = *(const float4*)(slabs + i);
    float4 b = *(const float4*)(slabs + N + i);
    float4 c = *(const float4*)(slabs + 2*N + i);
    float4 d = *(const float4*)(slabs + 3*N + i);
    float4 w;
    w.x = a.x + b.x + c.x + d.x;
    w.y = a.y + b.y + c.y + d.y;
    w.z = a.z + b.z + c.z + d.z;
    w.w = a.w + b.w + c.w + d.w;
    *(float4*)(out + i) = w;
}

// ---------------------------------------------------------------------------
// Split-K flash causal attention (round 16): R14's verified barrier/DMA
// schedule + 32x32x16 QK (layouts HW-verified in R13). Rationale: attn's LDS
// port is saturated (~240 KB/step ~ 2800 cyc = measured step time); dominant
// term is QK's 4x K-read amplification (128 KB). With 32x32 S-tiles each
// wave reads only its 32-key half: K reads 128 -> 64 KB/step.
// Spill fix vs R13: amdgpu_waves_per_eu(2,2) -- launch_bounds(256,2) only
// sets the MIN, and the allocator targeted 4 waves/EU @128 VGPR and spilled
// (R13: +31 MB WRITE_SIZE). max=2 unlocks the 256-VGPR budget; LDS caps us
// at 2 blocks/CU anyway, so nothing is lost.
//   QK: wave (rh=w>>1, kh=w&1): S[rh*32..+32][kh*32..+32], 16x mfma 32x32x16.
//   PV: col-split (R10/R14): all 64 rows x wave's 64-col strip, 16x 32x32.
// C/D: col=lane&31, row=(reg&3)+8*(reg>>2)+4*(lane>>5)  [m74/m101]
// A/B: m=lane&31, k=(lane>>5)*8+j                        [R13-verified]
// ---------------------------------------------------------------------------
__global__ __launch_bounds__(256) __attribute__((amdgpu_waves_per_eu(2, 2)))
void attn_kernel(const bf16* __restrict__ Qg,
                 const bf16* __restrict__ Kg,
                 const bf16* __restrict__ VTg,
                 bf16* __restrict__ Ret,
                 bf16* __restrict__ Opart,
                 float* __restrict__ Lpart)
{
    __shared__ __align__(16) bf16 Ks [64 * 256];   // 32 KB, swizzle c^(row&31)
    __shared__ __align__(16) bf16 VTs[256 * 64];   // 32 KB, swizzle c^(e&7)
    __shared__ __align__(16) bf16 Ps [64 * 72];    // 9 KB, padded

    static const unsigned char order[63] = {
        10,29,31,32,57,60,61,
        9,25,27,28,30,48,51,52,54,55,56,58,59,62,
        8,21,23,24,26,39,42,43,45,46,47,49,50,53,
        7,17,19,20,22,33,34,36,37,38,40,41,44,
        6,13,15,16,18,35,
        5,11,12,14,
        4,3,2,1,0 };

    const int tid  = threadIdx.x;
    const int lane = tid & 63;
    const int wave = tid >> 6;
    const int l32  = lane & 31;
    const int half = lane >> 5;            // 0|1
    const int rh   = wave >> 1;            // QK row-half
    const int kh   = wave & 1;             // QK key-half
    const int cw   = wave << 6;            // PV col strip

    // ---- uniform-length work mapping (R12-verified) ----
    const int bx  = blockIdx.x;                      // 0..1007
    const int bh  = bx & 15;
    const int bid = order[bx >> 4];                  // 0..62
    int qt, s, nsp;
    if (bid <= 10)      { qt = bid;                    s = 0;       nsp = 1; }
    else if (bid <= 32) { int k = bid - 11; qt = 11 + (k >> 1); s = k & 1; nsp = 2; }
    else                { int k = bid - 33; int q3 = k / 3; qt = 22 + q3; s = k - 3*q3; nsp = 3; }
    const int b = bh >> 3, h = bh & 7;

    const int S2 = qt + 1;                 // total 64-key steps
    const int base = S2 / nsp, rem = S2 - nsp*base;
    const int kstep0 = s*base + (s < rem ? s : rem);
    const int kstep1 = kstep0 + base + (s < rem ? 1 : 0);

    const bf16* Qbh  = Qg  + (size_t)(b*NH + h) * S_LEN * DIM;
    const bf16* Kbh  = Kg  + (size_t)(b*NH + h) * S_LEN * DIM;
    const bf16* VTbh = VTg + (size_t)(b*NH + h) * DIM * S_LEN;

    const int qbase32 = qt*64 + rh*32;     // this wave's 32 QK rows

    // Preload 32 Q rows as 16 A-frags (K=256; k = kc*16 + half*8 + j)
    bf16x8 qf[16];
    #pragma unroll
    for (int kc = 0; kc < 16; ++kc)
        qf[kc] = *(const bf16x8*)(Qbh + (size_t)(qbase32 + l32)*DIM + kc*16 + half*8);

    f32x16 o[4] = {};                      // [rt*2+ct]: 64 rows x 64-col strip
    float l_part[16] = {};

    // prologue: issue K(kstep0) (64x256 = 2048 chunks, 8 cp16/wave)
    {
        const int t00 = kstep0 << 6;
        #pragma unroll
        for (int j = 0; j < 8; ++j) {
            const int sN = ((wave*8 + j) << 6) + lane;
            const int ts = sN >> 5, cs = sN & 31;
            cp16(Kbh + (size_t)(t00 + ts)*DIM + ((cs ^ (ts & 31)) << 3),
                 Ks + ((wave*8 + j) << 9));
        }
    }

    for (int step = kstep0; step < kstep1; ++step) {
        const int t0 = step << 6;
        // (A) prev PV reads of VTs/Ps complete (raw barrier: keep K in flight)
        asm volatile("s_barrier" ::: "memory");
        // issue V(t): 256x64 = 2048 chunks, 8 cp16/wave
        #pragma unroll
        for (int j = 0; j < 8; ++j) {
            const int sN = ((wave*8 + j) << 6) + lane;
            const int es = sN >> 3, cs = sN & 7;
            cp16(VTbh + (size_t)es*S_LEN + t0 + ((cs ^ (es & 7)) << 3),
                 VTs + ((wave*8 + j) << 9));
        }
        // (B) wait K(t) only (8 newest = V stay outstanding); align waves
        asm volatile("s_waitcnt vmcnt(8)\n\ts_barrier" ::: "memory");

        // QK: 32 rows x 32 keys, 16-chained 32x32x16 (K-frags: one key-half)
        f32x16 sacc = {};
        #pragma unroll
        for (int kc = 0; kc < 16; ++kc) {
            const int ch  = kc*2 + half;
            const int row = kh*32 + l32;
            bf16x8 kf = *(const bf16x8*)(Ks + row*256 + ((ch ^ (row & 31)) << 3));
            sacc = __builtin_amdgcn_mfma_f32_32x32x16_bf16(qf[kc], kf, sacc, 0, 0, 0);
        }

        // softmax (no-max): p = exp(s/16) masked; row-sums; write P to Ps
        const int tg = t0 + kh*32 + l32;
        #pragma unroll
        for (int r = 0; r < 16; ++r) {
            const int lrow = rh*32 + 4*half + (r & 3) + 8*(r >> 2);
            const int qgi  = qt*64 + lrow;
            float p = (tg <= qgi) ? __expf(sacc[r] * 0.0625f) : 0.0f;
            l_part[r] += p;
            Ps[lrow*72 + kh*32 + l32] = (bf16)p;
        }
        // (C) Ps visible; QK reads of Ks done; V(t) drained (implicit vmcnt 0)
        __syncthreads();

        // issue K(t+1) into Ks (safe: PV never reads Ks)
        if (step + 1 < kstep1) {
            const int t1 = (step + 1) << 6;
            #pragma unroll
            for (int j = 0; j < 8; ++j) {
                const int sN = ((wave*8 + j) << 6) + lane;
                const int ts = sN >> 5, cs = sN & 31;
                cp16(Kbh + (size_t)(t1 + ts)*DIM + ((cs ^ (ts & 31)) << 3),
                     Ks + ((wave*8 + j) << 9));
            }
        }

        // PV col-split: all 64 rows x this wave's 64-col strip, 32x32x16.
        // pf: rt 2 x kc 4 (shared over ct); vf: ct 2 x kc 4 (shared over rt).
        bf16x8 pf[2][4];
        #pragma unroll
        for (int rt = 0; rt < 2; ++rt)
            #pragma unroll
            for (int kc = 0; kc < 4; ++kc)
                pf[rt][kc] = *(const bf16x8*)(Ps + (rt*32 + l32)*72 + kc*16 + half*8);
        #pragma unroll
        for (int ct = 0; ct < 2; ++ct) {
            #pragma unroll
            for (int kc = 0; kc < 4; ++kc) {
                const int e = cw + ct*32 + l32;
                const int g = kc*2 + half;
                bf16x8 vf = *(const bf16x8*)(VTs + (size_t)e*64 + ((g ^ (e & 7)) << 3));
                #pragma unroll
                for (int rt = 0; rt < 2; ++rt)
                    o[rt*2 + ct] = __builtin_amdgcn_mfma_f32_32x32x16_bf16(pf[rt][kc], vf, o[rt*2 + ct], 0, 0, 0);
            }
        }
    }

    // reduce l over the 32 key-lanes (same (half,r) group spans l32 0..31)
    #pragma unroll
    for (int r = 0; r < 16; ++r) {
        float l = l_part[r];
        l += __shfl_xor(l, 1);
        l += __shfl_xor(l, 2);
        l += __shfl_xor(l, 4);
        l += __shfl_xor(l, 8);
        l += __shfl_xor(l, 16);
        l_part[r] = l;
    }

    __syncthreads();                       // PV reads of Ps done -> alias Lp
    float* Lp = (float*)Ps;                // [2 kh][64 rows]
    if (l32 == 0) {
        #pragma unroll
        for (int r = 0; r < 16; ++r) {
            const int lrow = rh*32 + 4*half + (r & 3) + 8*(r >> 2);
            Lp[kh*64 + lrow] = l_part[r];
        }
    }
    __syncthreads();

    if (nsp == 1) {
        #pragma unroll
        for (int rt = 0; rt < 2; ++rt)
            #pragma unroll
            for (int r = 0; r < 16; ++r) {
                const int row = rt*32 + 4*half + (r & 3) + 8*(r >> 2);
                const float inv = 1.0f / (Lp[row] + Lp[64 + row]);
                #pragma unroll
                for (int ct = 0; ct < 2; ++ct)
                    Ret[((size_t)b*S_LEN + qt*64 + row)*HDIM + h*DIM + cw + ct*32 + l32]
                        = (bf16)(o[rt*2 + ct][r] * inv);
            }
    } else {
        const int slotbase = (qt <= 21) ? ((qt - 11)*2 + s) : (22 + (qt - 22)*3 + s);
        const size_t slot = (size_t)bh*52 + slotbase;
        bf16*  Ob = Opart + slot * (64*256);
        float* Lb = Lpart + slot * 64;
        if (tid < 64) Lb[tid] = Lp[tid] + Lp[64 + tid];
        #pragma unroll
        for (int rt = 0; rt < 2; ++rt)
            #pragma unroll
            for (int r = 0; r < 16; ++r) {
                const int row = rt*32 + 4*half + (r & 3) + 8*(r >> 2);
                #pragma unroll
                for (int ct = 0; ct < 2; ++ct)
                    Ob[(size_t)row*256 + cw + ct*32 + l32] = (bf16)o[rt*2 + ct][r];
            }
    }
}

// Sum the 2 or 3 partials of each split q-tile, normalize, write Ret.
// grid = 16 bh x 21 tiles = 336 blocks, 256 threads. [R12-verified]
__global__ __launch_bounds__(256) void combine_kernel(const bf16* __restrict__ Opart,
                                                      const float* __restrict__ Lpart,
                                                      bf16* __restrict__ Ret)
{
    const int bx = blockIdx.x;
    const int bh = bx / 21;
    const int ti = bx - bh*21;
    const int qt = 11 + ti;
    const int n  = (qt <= 21) ? 2 : 3;
    const int slotbase = (qt <= 21) ? (qt - 11)*2 : (22 + (qt - 22)*3);
    const size_t slot0 = (size_t)bh*52 + slotbase;
    const int b = bh >> 3, h = bh & 7;
    const int row  = threadIdx.x >> 2;
    const int col0 = (threadIdx.x & 3) * 64;

    float l = 0.f;
    for (int i = 0; i < n; ++i) l += Lpart[(slot0 + i)*64 + row];
    const float inv = 1.0f / l;

    const bf16* O0 = Opart + slot0 * (64*256) + (size_t)row*256 + col0;
    const int q = qt*64 + row;
    bf16* dst = Ret + ((size_t)b*S_LEN + q)*HDIM + h*DIM + col0;
    #pragma unroll
    for (int ch = 0; ch < 8; ++ch) {
        float acc[8] = {};
        for (int i = 0; i < n; ++i) {
            bf16x8 a = *(const bf16x8*)(O0 + (size_t)i*(64*256) + ch*8);
            #pragma unroll
            for (int j = 0; j < 8; ++j) acc[j] += (float)a[j];
        }
        bf16x8 w;
        #pragma unroll
        for (int j = 0; j < 8; ++j) w[j] = (bf16)(acc[j] * inv);
        *(bf16x8*)(dst + ch*8) = w;
    }
}

// ---------------------------------------------------------------------------

extern "C" void kernel_launch(void* const* d_in, const int* in_sizes, int n_in,
                              void* d_out, int out_size, void* d_ws, size_t ws_size,
                              hipStream_t stream)
{
    (void)in_sizes; (void)n_in; (void)out_size; (void)ws_size;
    const float* X  = (const float*)d_in[0];
    // d_in[1] timestamp, d_in[6] theta: dead code in reference output
    const float* wQ = (const float*)d_in[2];
    const float* wK = (const float*)d_in[3];
    const float* wV = (const float*)d_in[4];
    const float* wO = (const float*)d_in[5];

    char* ws = (char*)d_ws;
    const size_t MB = 1u << 20;
    bf16*  Xb    = (bf16*)(ws + 0*MB);    // [B,S,D]        2 MB
    bf16*  WQt   = (bf16*)(ws + 2*MB);    // [H,E,D]        1 MB
    bf16*  WKt   = (bf16*)(ws + 3*MB);
    bf16*  WVt   = (bf16*)(ws + 4*MB);
    bf16*  WOt   = (bf16*)(ws + 5*MB);    // [D,H*D]        1 MB
    bf16*  Qg    = (bf16*)(ws + 6*MB);    // [B,H,S,D]     16 MB (dead after attn)
    bf16*  Kg    = (bf16*)(ws + 22*MB);   // [B,H,S,D]     16 MB
    bf16*  VTg   = (bf16*)(ws + 38*MB);   // [B,H,D,S]     16 MB
    bf16*  Ret   = (bf16*)(ws + 54*MB);   // [B,S,H*D]     16 MB
    bf16*  Opart = (bf16*)(ws + 70*MB);   // 832 slots x 64x256 bf16 = 27.25 MB
    float* Lpart = (float*)(ws + 98*MB);  // 832 x 64 fp32 = 208 KB
    float* slabs = (float*)Qg;            // reuse dead Qg: 4 x 4 MB fp32 = 16 MB

    prep_kernel    <<<dim3(4, 32, 5), 256, 0, stream>>>(X, wQ, wK, wV, wO,
                                                        Xb, WQt, WKt, WVt, WOt);
    proj_kernel    <<<dim3(32, 48), 256, 0, stream>>>(Xb, WQt, WKt, WVt, Qg, Kg, VTg);
    attn_kernel    <<<1008,         256, 0, stream>>>(Qg, Kg, VTg, Ret, Opart, Lpart);
    combine_kernel <<<336,          256, 0, stream>>>(Opart, Lpart, Ret);
    outproj_kernel <<<256,          256, 0, stream>>>(Ret, WOt, slabs);
    reduce_out_kernel<<<1024,       256, 0, stream>>>(slabs, (float*)d_out);
}

// Round 17
// 183.908 us; speedup vs baseline: 1.3606x; 1.3606x over previous
//
#include <hip/hip_runtime.h>
#include <cstdint>
#include <cstddef>

// Problem constants (B,S,D,H) = (2, 2048, 256, 8)
#define S_LEN 2048
#define DIM   256
#define NH    8
#define NB    2
#define HDIM  (NH * DIM)   // 2048

using bf16 = __bf16;
typedef __bf16 bf16x8 __attribute__((ext_vector_type(8)));
typedef __bf16 bf16x4 __attribute__((ext_vector_type(4)));
typedef float  f32x4  __attribute__((ext_vector_type(4)));

typedef const __attribute__((address_space(1))) unsigned int* as1_u32p;
typedef __attribute__((address_space(3))) unsigned int* as3_u32p;

// async 16B global -> LDS (no VGPR round-trip). LDS dest = wave-uniform base
// + lane*16 (m104/m108).
__device__ __forceinline__ void cp16(const bf16* g, bf16* l) {
    __builtin_amdgcn_global_load_lds((as1_u32p)g, (as3_u32p)l, 16, 0, 0);
}

// ---------------------------------------------------------------------------
// Fused prep (one launch): z=0..2 -> wQ/wK/wV transpose-cast (h = y>>2),
// z=3 -> wO transpose-cast, z=4 -> X fp32->bf16 cast. grid dim3(4,32,5).
// ---------------------------------------------------------------------------
__global__ __launch_bounds__(256) void prep_kernel(const float* __restrict__ X,
                                                   const float* __restrict__ wQ,
                                                   const float* __restrict__ wK,
                                                   const float* __restrict__ wV,
                                                   const float* __restrict__ wO,
                                                   bf16* __restrict__ Xb,
                                                   bf16* __restrict__ WQt,
                                                   bf16* __restrict__ WKt,
                                                   bf16* __restrict__ WVt,
                                                   bf16* __restrict__ WOt)
{
    const int z = blockIdx.z;
    if (z == 4) {                     // cast X
        const int t = (blockIdx.y*4 + blockIdx.x)*256 + threadIdx.x;   // 0..32767
        #pragma unroll
        for (int p = 0; p < 8; ++p) {
            const int i = (t + p*32768)*4;
            float4 v = *(const float4*)(X + i);
            bf16x4 o;
            o[0] = (bf16)v.x; o[1] = (bf16)v.y; o[2] = (bf16)v.z; o[3] = (bf16)v.w;
            *(bf16x4*)(Xb + i) = o;
        }
        return;
    }
    __shared__ float tile[64][65];
    const float* in; bf16* out; int R, C, r0, c0;
    if (z < 3) {
        const int h = blockIdx.y >> 2;
        in  = (z == 0 ? wQ : z == 1 ? wK : wV) + (size_t)h * DIM * DIM;
        out = (z == 0 ? WQt : z == 1 ? WKt : WVt) + (size_t)h * DIM * DIM;
        R = DIM; C = DIM; r0 = (blockIdx.y & 3) * 64; c0 = blockIdx.x * 64;
    } else {
        in = wO; out = WOt; R = HDIM; C = DIM;
        r0 = blockIdx.y * 64; c0 = blockIdx.x * 64;
    }
    const int tr  = threadIdx.x >> 4;
    const int tc4 = (threadIdx.x & 15) * 4;
    #pragma unroll
    for (int p = 0; p < 4; ++p) {
        int row = p * 16 + tr;
        float4 v = *(const float4*)(in + (size_t)(r0 + row) * C + c0 + tc4);
        tile[row][tc4+0] = v.x; tile[row][tc4+1] = v.y;
        tile[row][tc4+2] = v.z; tile[row][tc4+3] = v.w;
    }
    __syncthreads();
    #pragma unroll
    for (int p = 0; p < 4; ++p) {
        int orow = p * 16 + tr;
        bf16x4 o;
        #pragma unroll
        for (int j = 0; j < 4; ++j) o[j] = (bf16)tile[tc4 + j][orow];
        *(bf16x4*)(out + (size_t)(c0 + orow) * R + r0 + tc4) = o;
    }
}

// ---------------------------------------------------------------------------
// 128x128-tile bf16 MFMA GEMM, ROUND-8/14-verified (async-DMA, XOR swizzle,
// single barrier per k-step). EPI: 0 bf16, 1 f32 store.
// ---------------------------------------------------------------------------
template<int EPI>
__device__ __forceinline__ void gemm_tile(const bf16* __restrict__ A, const bf16* __restrict__ BT,
                                          void* __restrict__ C, bf16* As, bf16* Bs,
                                          int tm, int tn, int K, int lda, int ldb, int ldc)
{
    const int tid  = threadIdx.x;
    const int lane = tid & 63;
    const int wave = tid >> 6;
    const int wm   = (wave >> 1) << 6;
    const int wn   = (wave & 1) << 6;
    const int l16  = lane & 15;
    const int quad = lane >> 4;

    const int m0 = tm << 7, n0 = tn << 7;

    const int srow = (lane >> 2);
    const int gch  = (lane & 3) ^ (srow & 3);

    f32x4 acc[4][4] = {};

    const int ksteps = K >> 5;

    #pragma unroll
    for (int j = 0; j < 2; ++j) {
        const int g = wave*2 + j;
        cp16(A  + (size_t)(m0 + g*16 + srow)*lda + (gch << 3), As + g*512);
        cp16(BT + (size_t)(n0 + g*16 + srow)*ldb + (gch << 3), Bs + g*512);
    }

    for (int ks = 0; ks < ksteps; ++ks) {
        const int pb = ks & 1;
        asm volatile("s_waitcnt vmcnt(0)" ::: "memory");
        __syncthreads();
        if (ks + 1 < ksteps) {
            const int k1 = (ks + 1) << 5;
            #pragma unroll
            for (int j = 0; j < 2; ++j) {
                const int g = wave*2 + j;
                cp16(A  + (size_t)(m0 + g*16 + srow)*lda + k1 + (gch << 3),
                     As + (pb ^ 1)*4096 + g*512);
                cp16(BT + (size_t)(n0 + g*16 + srow)*ldb + k1 + (gch << 3),
                     Bs + (pb ^ 1)*4096 + g*512);
            }
        }
        const bf16* Ab = As + pb*4096;
        const bf16* Bb = Bs + pb*4096;
        bf16x8 af[4], bfv[4];
        #pragma unroll
        for (int i = 0; i < 4; ++i) {
            const int row = wm + i*16 + l16;
            af[i]  = *(const bf16x8*)(Ab + row*32 + ((quad ^ (l16 & 3)) << 3));
        }
        #pragma unroll
        for (int i = 0; i < 4; ++i) {
            const int row = wn + i*16 + l16;
            bfv[i] = *(const bf16x8*)(Bb + row*32 + ((quad ^ (l16 & 3)) << 3));
        }
        #pragma unroll
        for (int i = 0; i < 4; ++i)
            #pragma unroll
            for (int j = 0; j < 4; ++j)
                acc[i][j] = __builtin_amdgcn_mfma_f32_16x16x32_bf16(af[i], bfv[j], acc[i][j], 0, 0, 0);
    }

    #pragma unroll
    for (int i = 0; i < 4; ++i)
        #pragma unroll
        for (int j = 0; j < 4; ++j)
            #pragma unroll
            for (int r = 0; r < 4; ++r) {
                int mg = m0 + wm + i*16 + quad*4 + r;
                int ng = n0 + wn + j*16 + l16;
                float v = acc[i][j][r];
                if (EPI == 0) ((bf16*)C)[(size_t)mg * ldc + ng] = (bf16)v;
                else          ((float*)C)[(size_t)mg * ldc + ng] = v;
            }
}

// QKV projections. grid = (32 tiles, 48 = {Q,K,V} x b x h). LDS 32 KB.  [R14]
__global__ __launch_bounds__(256) void proj_kernel(const bf16* __restrict__ Xb,
    const bf16* __restrict__ WQt, const bf16* __restrict__ WKt, const bf16* __restrict__ WVt,
    bf16* __restrict__ Qg, bf16* __restrict__ Kg, bf16* __restrict__ VTg)
{
    __shared__ __align__(16) bf16 smem[4 * 4096];
    const int by  = blockIdx.y;
    const int mat = by >> 4;
    const int b   = (by >> 3) & 1;
    const int h   = by & 7;
    const int bx  = blockIdx.x;
    const bf16*  Xbb = Xb + (size_t)b * S_LEN * DIM;
    const size_t bh  = (size_t)(b * NH + h);
    if (mat == 0) {
        gemm_tile<0>(Xbb, WQt + (size_t)h*DIM*DIM, Qg + bh*S_LEN*DIM, smem, smem + 8192,
                     bx & 15, bx >> 4, DIM, DIM, DIM, DIM);
    } else if (mat == 1) {
        gemm_tile<0>(Xbb, WKt + (size_t)h*DIM*DIM, Kg + bh*S_LEN*DIM, smem, smem + 8192,
                     bx & 15, bx >> 4, DIM, DIM, DIM, DIM);
    } else {
        gemm_tile<0>(WVt + (size_t)h*DIM*DIM, Xbb, VTg + bh*DIM*S_LEN, smem, smem + 8192,
                     bx & 1, bx >> 1, DIM, DIM, DIM, S_LEN);
    }
}

// outproj to 4 fp32 slabs (no atomics): slab[kq][4096][256] = Ret@WOt k-slice. [R14]
__global__ __launch_bounds__(256) void outproj_kernel(const bf16* __restrict__ Ret,
                                                      const bf16* __restrict__ WOt,
                                                      float* __restrict__ slabs)
{
    __shared__ __align__(16) bf16 smem[4 * 4096];
    int bx = blockIdx.x;
    int t  = bx & 63;
    int kq = bx >> 6;
    gemm_tile<1>(Ret + kq*512, WOt + kq*512, slabs + (size_t)kq*4096*256,
                 smem, smem + 8192, t >> 1, t & 1, 512, HDIM, HDIM, DIM);
}

// sum 4 slabs -> d_out. 1024 blocks x 256 thr x float4. [R14]
__global__ __launch_bounds__(256) void reduce_out_kernel(const float* __restrict__ slabs,
                                                         float* __restrict__ out)
{
    const size_t i = ((size_t)blockIdx.x*256 + threadIdx.x)*4;
    const size_t N = (size_t)4096*256;
    float4 a = *(const float4*)(slabs + i);
    float4 b = *(const float4*)(slabs + N + i);
    float4 c = *(const float4*)(slabs + 2*N + i);
    float4 d = *(const float4*)(slabs + 3*N + i);
    float4 w;
    w.x = a.x + b.x + c.x + d.x;
    w.y = a.y + b.y + c.y + d.y;
    w.z = a.z + b.z + c.z + d.z;
    w.w = a.w + b.w + c.w + d.w;
    *(float4*)(out + i) = w;
}

// ---------------------------------------------------------------------------
// Split-K flash causal attention — ROUND-14-verified optimum, byte-identical.
// 64-key steps; 2 barriers + 1 explicit vmcnt wait per step; col-split PV;
// XOR swizzles; uniform-length split-K partition, longest-first dispatch.
// ---------------------------------------------------------------------------
__global__ __launch_bounds__(256, 2) void attn_kernel(const bf16* __restrict__ Qg,
                                                      const bf16* __restrict__ Kg,
                                                      const bf16* __restrict__ VTg,
                                                      bf16* __restrict__ Ret,
                                                      bf16* __restrict__ Opart,
                                                      float* __restrict__ Lpart)
{
    __shared__ __align__(16) bf16 Ks [64 * 256];   // 32 KB, swizzle c^(row&31)
    __shared__ __align__(16) bf16 VTs[256 * 64];   // 32 KB, swizzle c^(e&7)
    __shared__ __align__(16) bf16 Ps [64 * 72];    // 9 KB, padded

    static const unsigned char order[63] = {
        10,29,31,32,57,60,61,
        9,25,27,28,30,48,51,52,54,55,56,58,59,62,
        8,21,23,24,26,39,42,43,45,46,47,49,50,53,
        7,17,19,20,22,33,34,36,37,38,40,41,44,
        6,13,15,16,18,35,
        5,11,12,14,
        4,3,2,1,0 };

    const int tid  = threadIdx.x;
    const int lane = tid & 63;
    const int wave = tid >> 6;
    const int l16  = lane & 15;
    const int quad = lane >> 4;
    const int cw   = wave << 6;            // PV col strip

    const int bx  = blockIdx.x;                      // 0..1007
    const int bh  = bx & 15;
    const int bid = order[bx >> 4];                  // 0..62
    int qt, s, nsp;
    if (bid <= 10)      { qt = bid;                    s = 0;       nsp = 1; }
    else if (bid <= 32) { int k = bid - 11; qt = 11 + (k >> 1); s = k & 1; nsp = 2; }
    else                { int k = bid - 33; int q3 = k / 3; qt = 22 + q3; s = k - 3*q3; nsp = 3; }
    const int b = bh >> 3, h = bh & 7;

    const int S2 = qt + 1;                 // total 64-key steps
    const int base = S2 / nsp, rem = S2 - nsp*base;
    const int kstep0 = s*base + (s < rem ? s : rem);
    const int kstep1 = kstep0 + base + (s < rem ? 1 : 0);

    const bf16* Qbh  = Qg  + (size_t)(b*NH + h) * S_LEN * DIM;
    const bf16* Kbh  = Kg  + (size_t)(b*NH + h) * S_LEN * DIM;
    const bf16* VTbh = VTg + (size_t)(b*NH + h) * DIM * S_LEN;

    const int qbase = qt*64 + wave*16;     // QK: this wave's 16 rows

    bf16x8 qf[8];
    #pragma unroll
    for (int kc = 0; kc < 8; ++kc)
        qf[kc] = *(const bf16x8*)(Qbh + (size_t)(qbase + l16)*DIM + kc*32 + quad*8);

    f32x4 o[16] = {};                      // [rt*4+ct]: 64 rows x 64 cols (strip)
    float l_part[4] = {0.f, 0.f, 0.f, 0.f};

    {
        const int t00 = kstep0 << 6;
        #pragma unroll
        for (int j = 0; j < 8; ++j) {
            const int sN = ((wave*8 + j) << 6) + lane;
            const int ts = sN >> 5, cs = sN & 31;
            cp16(Kbh + (size_t)(t00 + ts)*DIM + ((cs ^ (ts & 31)) << 3),
                 Ks + ((wave*8 + j) << 9));
        }
    }

    for (int step = kstep0; step < kstep1; ++step) {
        const int t0 = step << 6;
        asm volatile("s_barrier" ::: "memory");
        #pragma unroll
        for (int j = 0; j < 8; ++j) {
            const int sN = ((wave*8 + j) << 6) + lane;
            const int es = sN >> 3, cs = sN & 7;
            cp16(VTbh + (size_t)es*S_LEN + t0 + ((cs ^ (es & 7)) << 3),
                 VTs + ((wave*8 + j) << 9));
        }
        asm volatile("s_waitcnt vmcnt(8)\n\ts_barrier" ::: "memory");

        f32x4 sacc[4] = {};
        #pragma unroll
        for (int kc = 0; kc < 8; ++kc) {
            const int ch = (kc << 2) + quad;
            #pragma unroll
            for (int kt = 0; kt < 4; ++kt) {
                const int row = kt*16 + l16;
                bf16x8 kf = *(const bf16x8*)(Ks + row*256 + ((ch ^ (row & 31)) << 3));
                sacc[kt] = __builtin_amdgcn_mfma_f32_16x16x32_bf16(qf[kc], kf, sacc[kt], 0,0,0);
            }
        }

        #pragma unroll
        for (int kt = 0; kt < 4; ++kt) {
            const int tg = t0 + kt*16 + l16;
            #pragma unroll
            for (int r = 0; r < 4; ++r) {
                const int qgi = qbase + quad*4 + r;
                float p = (tg <= qgi) ? __expf(sacc[kt][r] * 0.0625f) : 0.0f;
                l_part[r] += p;
                Ps[(wave*16 + quad*4 + r)*72 + kt*16 + l16] = (bf16)p;
            }
        }
        __syncthreads();

        if (step + 1 < kstep1) {
            const int t1 = (step + 1) << 6;
            #pragma unroll
            for (int j = 0; j < 8; ++j) {
                const int sN = ((wave*8 + j) << 6) + lane;
                const int ts = sN >> 5, cs = sN & 31;
                cp16(Kbh + (size_t)(t1 + ts)*DIM + ((cs ^ (ts & 31)) << 3),
                     Ks + ((wave*8 + j) << 9));
            }
        }

        #pragma unroll
        for (int kc2 = 0; kc2 < 2; ++kc2) {
            bf16x8 pf[4];
            #pragma unroll
            for (int rt = 0; rt < 4; ++rt)
                pf[rt] = *(const bf16x8*)(Ps + (rt*16 + l16)*72 + kc2*32 + quad*8);
            #pragma unroll
            for (int ct = 0; ct < 4; ++ct) {
                const int e = cw + ct*16 + l16;
                const int g = (kc2 << 2) + quad;
                bf16x8 vf = *(const bf16x8*)(VTs + e*64 + ((g ^ (e & 7)) << 3));
                #pragma unroll
                for (int rt = 0; rt < 4; ++rt)
                    o[rt*4 + ct] = __builtin_amdgcn_mfma_f32_16x16x32_bf16(pf[rt], vf, o[rt*4 + ct], 0,0,0);
            }
        }
    }

    float lsum[4];
    #pragma unroll
    for (int r = 0; r < 4; ++r) {
        float l = l_part[r];
        l += __shfl_xor(l, 1);
        l += __shfl_xor(l, 2);
        l += __shfl_xor(l, 4);
        l += __shfl_xor(l, 8);
        lsum[r] = l;
    }

    __syncthreads();
    float* Lp = (float*)Ps;
    if (l16 == 0) {
        #pragma unroll
        for (int r = 0; r < 4; ++r) Lp[wave*16 + quad*4 + r] = lsum[r];
    }
    __syncthreads();

    if (nsp == 1) {
        #pragma unroll
        for (int rt = 0; rt < 4; ++rt)
            #pragma unroll
            for (int r = 0; r < 4; ++r) {
                const int row = rt*16 + quad*4 + r;
                const float inv = 1.0f / Lp[row];
                #pragma unroll
                for (int ct = 0; ct < 4; ++ct)
                    Ret[((size_t)b*S_LEN + qt*64 + row)*HDIM + h*DIM + cw + ct*16 + l16]
                        = (bf16)(o[rt*4 + ct][r] * inv);
            }
    } else {
        const int slotbase = (qt <= 21) ? ((qt - 11)*2 + s) : (22 + (qt - 22)*3 + s);
        const size_t slot = (size_t)bh*52 + slotbase;
        bf16*  Ob = Opart + slot * (64*256);
        float* Lb = Lpart + slot * 64;
        if (l16 == 0) {
            #pragma unroll
            for (int r = 0; r < 4; ++r) Lb[wave*16 + quad*4 + r] = lsum[r];
        }
        #pragma unroll
        for (int rt = 0; rt < 4; ++rt)
            #pragma unroll
            for (int r = 0; r < 4; ++r) {
                const int row = rt*16 + quad*4 + r;
                #pragma unroll
                for (int ct = 0; ct < 4; ++ct)
                    Ob[(size_t)row*256 + cw + ct*16 + l16] = (bf16)o[rt*4 + ct][r];
            }
    }
}

// Sum the 2 or 3 partials of each split q-tile, normalize, write Ret.
// grid = 16 bh x 21 tiles = 336 blocks, 256 threads. [R12-verified]
__global__ __launch_bounds__(256) void combine_kernel(const bf16* __restrict__ Opart,
                                                      const float* __restrict__ Lpart,
                                                      bf16* __restrict__ Ret)
{
    const int bx = blockIdx.x;
    const int bh = bx / 21;
    const int ti = bx - bh*21;
    const int qt = 11 + ti;
    const int n  = (qt <= 21) ? 2 : 3;
    const int slotbase = (qt <= 21) ? (qt - 11)*2 : (22 + (qt - 22)*3);
    const size_t slot0 = (size_t)bh*52 + slotbase;
    const int b = bh >> 3, h = bh & 7;
    const int row  = threadIdx.x >> 2;
    const int col0 = (threadIdx.x & 3) * 64;

    float l = 0.f;
    for (int i = 0; i < n; ++i) l += Lpart[(slot0 + i)*64 + row];
    const float inv = 1.0f / l;

    const bf16* O0 = Opart + slot0 * (64*256) + (size_t)row*256 + col0;
    const int q = qt*64 + row;
    bf16* dst = Ret + ((size_t)b*S_LEN + q)*HDIM + h*DIM + col0;
    #pragma unroll
    for (int ch = 0; ch < 8; ++ch) {
        float acc[8] = {};
        for (int i = 0; i < n; ++i) {
            bf16x8 a = *(const bf16x8*)(O0 + (size_t)i*(64*256) + ch*8);
            #pragma unroll
            for (int j = 0; j < 8; ++j) acc[j] += (float)a[j];
        }
        bf16x8 w;
        #pragma unroll
        for (int j = 0; j < 8; ++j) w[j] = (bf16)(acc[j] * inv);
        *(bf16x8*)(dst + ch*8) = w;
    }
}

// ---------------------------------------------------------------------------

extern "C" void kernel_launch(void* const* d_in, const int* in_sizes, int n_in,
                              void* d_out, int out_size, void* d_ws, size_t ws_size,
                              hipStream_t stream)
{
    (void)in_sizes; (void)n_in; (void)out_size; (void)ws_size;
    const float* X  = (const float*)d_in[0];
    // d_in[1] timestamp, d_in[6] theta: dead code in reference output
    const float* wQ = (const float*)d_in[2];
    const float* wK = (const float*)d_in[3];
    const float* wV = (const float*)d_in[4];
    const float* wO = (const float*)d_in[5];

    char* ws = (char*)d_ws;
    const size_t MB = 1u << 20;
    bf16*  Xb    = (bf16*)(ws + 0*MB);    // [B,S,D]        2 MB
    bf16*  WQt   = (bf16*)(ws + 2*MB);    // [H,E,D]        1 MB
    bf16*  WKt   = (bf16*)(ws + 3*MB);
    bf16*  WVt   = (bf16*)(ws + 4*MB);
    bf16*  WOt   = (bf16*)(ws + 5*MB);    // [D,H*D]        1 MB
    bf16*  Qg    = (bf16*)(ws + 6*MB);    // [B,H,S,D]     16 MB (dead after attn)
    bf16*  Kg    = (bf16*)(ws + 22*MB);   // [B,H,S,D]     16 MB
    bf16*  VTg   = (bf16*)(ws + 38*MB);   // [B,H,D,S]     16 MB
    bf16*  Ret   = (bf16*)(ws + 54*MB);   // [B,S,H*D]     16 MB
    bf16*  Opart = (bf16*)(ws + 70*MB);   // 832 slots x 64x256 bf16 = 27.25 MB
    float* Lpart = (float*)(ws + 98*MB);  // 832 x 64 fp32 = 208 KB
    float* slabs = (float*)Qg;            // reuse dead Qg: 4 x 4 MB fp32 = 16 MB

    prep_kernel    <<<dim3(4, 32, 5), 256, 0, stream>>>(X, wQ, wK, wV, wO,
                                                        Xb, WQt, WKt, WVt, WOt);
    proj_kernel    <<<dim3(32, 48), 256, 0, stream>>>(Xb, WQt, WKt, WVt, Qg, Kg, VTg);
    attn_kernel    <<<1008,         256, 0, stream>>>(Qg, Kg, VTg, Ret, Opart, Lpart);
    combine_kernel <<<336,          256, 0, stream>>>(Opart, Lpart, Ret);
    outproj_kernel <<<256,          256, 0, stream>>>(Ret, WOt, slabs);
    reduce_out_kernel<<<1024,       256, 0, stream>>>(slabs, (float*)d_out);
}